// Round 12
// baseline (543.304 us; speedup 1.0000x reference)
//
#include <hip/hip_runtime.h>
#include <hip/hip_bf16.h>
#include <math.h>

// Problem constants: B=4, S=2048, D=256, H=8, DK=32, L=4, FF=512
#define SEQ 2048
#define DIM 256
#define NH 8
#define DK 32
#define FF 512

typedef __bf16 bf16_t;
typedef bf16_t bf16x8 __attribute__((ext_vector_type(8)));
typedef bf16_t bf16x4 __attribute__((ext_vector_type(4)));
typedef float f32x4 __attribute__((ext_vector_type(4)));

// Q pre-scaled by (1/sqrt(DK)) * log2(e); softmax exp becomes v_exp_f32 (2^x).
#define QK_SCALE_LOG2 0.25503226632462494f
#if __has_builtin(__builtin_amdgcn_exp2f)
#define FAST_EXP2(x) __builtin_amdgcn_exp2f(x)
#else
#define FAST_EXP2(x) __expf((x) * 0.6931471805599453f)
#endif

// ---------------------------------------------------------------------------
// Double LayerNorm (start): h = LN(x,ln0); x2 = LN(h,ln1[0]).
// ---------------------------------------------------------------------------
__global__ __launch_bounds__(256) void ln_double_kernel(
    const float* __restrict__ x, const float* __restrict__ s0,
    const float* __restrict__ b0, const float* __restrict__ s1,
    const float* __restrict__ b1, float* __restrict__ outf,
    bf16_t* __restrict__ outb) {
  int wave = threadIdx.x >> 6;
  int lane = threadIdx.x & 63;
  int row = blockIdx.x * 4 + wave;
  float4 xv = *(const float4*)(x + (size_t)row * DIM + lane * 4);
  float sum = xv.x + xv.y + xv.z + xv.w;
  float sq = xv.x * xv.x + xv.y * xv.y + xv.z * xv.z + xv.w * xv.w;
#pragma unroll
  for (int off = 1; off < 64; off <<= 1) {
    sum += __shfl_xor(sum, off);
    sq += __shfl_xor(sq, off);
  }
  float mean = sum * (1.0f / 256.0f);
  float var = sq * (1.0f / 256.0f) - mean * mean;
  float inv = rsqrtf(var + 1e-5f);
  float4 sv = *(const float4*)(s0 + lane * 4);
  float4 bv = *(const float4*)(b0 + lane * 4);
  float4 h;
  h.x = (xv.x - mean) * inv * sv.x + bv.x;
  h.y = (xv.y - mean) * inv * sv.y + bv.y;
  h.z = (xv.z - mean) * inv * sv.z + bv.z;
  h.w = (xv.w - mean) * inv * sv.w + bv.w;
  *(float4*)(outf + (size_t)row * DIM + lane * 4) = h;
  float sum2 = h.x + h.y + h.z + h.w;
  float sq2 = h.x * h.x + h.y * h.y + h.z * h.z + h.w * h.w;
#pragma unroll
  for (int off = 1; off < 64; off <<= 1) {
    sum2 += __shfl_xor(sum2, off);
    sq2 += __shfl_xor(sq2, off);
  }
  float mean2 = sum2 * (1.0f / 256.0f);
  float var2 = sq2 * (1.0f / 256.0f) - mean2 * mean2;
  float inv2 = rsqrtf(var2 + 1e-5f);
  float4 s1v = *(const float4*)(s1 + lane * 4);
  float4 b1v = *(const float4*)(b1 + lane * 4);
  bf16x4 ob = {(bf16_t)((h.x - mean2) * inv2 * s1v.x + b1v.x),
               (bf16_t)((h.y - mean2) * inv2 * s1v.y + b1v.y),
               (bf16_t)((h.z - mean2) * inv2 * s1v.z + b1v.z),
               (bf16_t)((h.w - mean2) * inv2 * s1v.w + b1v.w)};
  *(bf16x4*)(outb + (size_t)row * DIM + lane * 4) = ob;
}

// ---------------------------------------------------------------------------
// All-weights transpose+convert in ONE dispatch (512 blocks).
// ---------------------------------------------------------------------------
__global__ __launch_bounds__(256) void wtrans_all_kernel(
    const float* __restrict__ wq, const float* __restrict__ wk,
    const float* __restrict__ wv, const float* __restrict__ wo,
    const float* __restrict__ w1, const float* __restrict__ w2,
    bf16_t* __restrict__ WqT, bf16_t* __restrict__ WkT,
    bf16_t* __restrict__ WvT, bf16_t* __restrict__ WoT,
    bf16_t* __restrict__ W1T, bf16_t* __restrict__ W2T) {
  __shared__ float tile[64][65];
  int idx = blockIdx.x;
  int layer = idx >> 7;
  int r = idx & 127;
  const float* src;
  bf16_t* dst;
  int N, k0, n0;
  if (r < 64) {
    int which = r >> 4, t = r & 15;
    N = 256;
    k0 = (t & 3) * 64;
    n0 = (t >> 2) * 64;
    src = (which == 0 ? wq : which == 1 ? wk : which == 2 ? wv : wo) + (size_t)layer * 65536;
    dst = (which == 0 ? WqT : which == 1 ? WkT : which == 2 ? WvT : WoT) + (size_t)layer * 65536;
  } else if (r < 96) {
    int t = r - 64;
    N = 512;
    k0 = (t & 3) * 64;
    n0 = (t >> 2) * 64;
    src = w1 + (size_t)layer * 131072;
    dst = W1T + (size_t)layer * 131072;
  } else {
    int t = r - 96;
    N = 256;
    k0 = (t & 7) * 64;
    n0 = (t >> 3) * 64;
    src = w2 + (size_t)layer * 131072;
    dst = W2T + (size_t)layer * 131072;
  }
  int K = (r >= 96) ? 512 : 256;

  int tr = threadIdx.x >> 4;
  int tc4 = (threadIdx.x & 15) * 4;
#pragma unroll
  for (int i = 0; i < 4; i++) {
    int kl = i * 16 + tr;
    float4 v = *(const float4*)(src + (size_t)(k0 + kl) * N + n0 + tc4);
    tile[kl][tc4 + 0] = v.x; tile[kl][tc4 + 1] = v.y;
    tile[kl][tc4 + 2] = v.z; tile[kl][tc4 + 3] = v.w;
  }
  __syncthreads();
#pragma unroll
  for (int i = 0; i < 4; i++) {
    int nl = i * 16 + tr;
    bf16x4 o = {(bf16_t)tile[tc4 + 0][nl], (bf16_t)tile[tc4 + 1][nl],
                (bf16_t)tile[tc4 + 2][nl], (bf16_t)tile[tc4 + 3][nl]};
    *(bf16x4*)(dst + (size_t)(n0 + nl) * K + k0 + tc4) = o;
  }
}

// ---------------------------------------------------------------------------
// Staging helpers (global_load_lds width=16, XOR chunk swizzle on source).
// ---------------------------------------------------------------------------
__device__ __forceinline__ void stage128(const bf16_t* __restrict__ src,
                                         bf16_t* dst, int tid, int ldk, int k0) {
#pragma unroll
  for (int u = 0; u < 4; u++) {
    int i = u * 256 + tid;
    int m = i >> 3, cd = i & 7, cs = cd ^ (m & 7);
    __builtin_amdgcn_global_load_lds(
        (const __attribute__((address_space(1))) unsigned int*)(src + (size_t)m * ldk + k0 + cs * 8),
        (__attribute__((address_space(3))) unsigned int*)(dst + i * 8), 16, 0, 0);
  }
}

// stages 256 rows x 64 k (32 KB)
__device__ __forceinline__ void stage256(const bf16_t* __restrict__ src,
                                         bf16_t* dst, int tid, int ldk, int k0) {
#pragma unroll
  for (int u = 0; u < 8; u++) {
    int j = u * 256 + tid;
    int m = j >> 3, cd = j & 7, cs = cd ^ (m & 7);
    __builtin_amdgcn_global_load_lds(
        (const __attribute__((address_space(1))) unsigned int*)(src + (size_t)m * ldk + k0 + cs * 8),
        (__attribute__((address_space(3))) unsigned int*)(dst + j * 8), 16, 0, 0);
  }
}

__device__ __forceinline__ void compute128(const bf16_t* As, const bf16_t* Bs,
                                           int wr, int wc, int n16, int quad,
                                           f32x4 (&acc)[4][4]) {
#pragma unroll
  for (int ks = 0; ks < 2; ks++) {
    bf16x8 af[4], bf[4];
#pragma unroll
    for (int mt = 0; mt < 4; mt++) {
      int row = wr * 64 + mt * 16 + n16;
      int cd = (ks * 4 + quad) ^ (row & 7);
      af[mt] = *(const bf16x8*)(As + row * 64 + cd * 8);
    }
#pragma unroll
    for (int nt = 0; nt < 4; nt++) {
      int row = wc * 64 + nt * 16 + n16;
      int cd = (ks * 4 + quad) ^ (row & 7);
      bf[nt] = *(const bf16x8*)(Bs + row * 64 + cd * 8);
    }
#pragma unroll
    for (int mt = 0; mt < 4; mt++)
#pragma unroll
      for (int nt = 0; nt < 4; nt++)
        acc[mt][nt] = __builtin_amdgcn_mfma_f32_16x16x32_bf16(
            af[mt], bf[nt], acc[mt][nt], 0, 0, 0);
  }
}

template <int K>
__device__ __forceinline__ void gemm9_body(
    const bf16_t* __restrict__ A, const bf16_t* __restrict__ BT,
    int m0, int n0, int tid, bf16_t* As, bf16_t* Bs, f32x4 (&acc)[4][4]) {
  int lane = tid & 63;
  int n16 = lane & 15, quad = lane >> 4;
  int w = tid >> 6;
  int wr = w >> 1, wc = w & 1;
  const bf16_t* Arow = A + (size_t)m0 * K;
  const bf16_t* Brow = BT + (size_t)n0 * K;

  stage128(Arow, As, tid, K, 0);
  stage128(Brow, Bs, tid, K, 0);

  const int steps = K / 64;
#pragma unroll
  for (int s = 0; s < steps; s++) {
    int buf = s & 1;
    if (s + 1 < steps) {
      stage128(Arow, As + (buf ^ 1) * 8192, tid, K, (s + 1) * 64);
      stage128(Brow, Bs + (buf ^ 1) * 8192, tid, K, (s + 1) * 64);
    }
    __syncthreads();
    compute128(As + buf * 8192, Bs + buf * 8192, wr, wc, n16, quad, acc);
    if (s + 2 < steps) __syncthreads();
  }
}

// ---------------------------------------------------------------------------
// Fused QKV projection (128x128 body): grid (6, 64).
// ---------------------------------------------------------------------------
__global__ __launch_bounds__(256) void qkv9_kernel(
    const bf16_t* __restrict__ A,
    const bf16_t* __restrict__ WqT, const bf16_t* __restrict__ WkT,
    const bf16_t* __restrict__ WvT,
    const float* __restrict__ bq, const float* __restrict__ bk,
    const float* __restrict__ bv,
    bf16_t* __restrict__ qo, bf16_t* __restrict__ ko,
    bf16_t* __restrict__ vo) {
  __shared__ __align__(16) bf16_t As[2 * 8192];
  __shared__ __align__(16) bf16_t Bs[2 * 8192];
  int which = blockIdx.x >> 1;
  int nblk = blockIdx.x & 1;
  const bf16_t* BT = (which == 0) ? WqT : (which == 1) ? WkT : WvT;
  const float* bias = (which == 0) ? bq : (which == 1) ? bk : bv;

  int tid = threadIdx.x;
  int lane = tid & 63;
  int n16 = lane & 15, quad = lane >> 4;
  int w = tid >> 6;
  int wr = w >> 1, wc = w & 1;
  int m0 = blockIdx.y * 128, n0 = nblk * 128;
  f32x4 acc[4][4] = {};
  gemm9_body<256>(A, BT, m0, n0, tid, As, Bs, acc);

#pragma unroll
  for (int nt = 0; nt < 4; nt++) {
    int n = n0 + wc * 64 + nt * 16 + n16;
    float bv_ = bias[n];
    int hh = n >> 5, dk = n & 31;
#pragma unroll
    for (int mt = 0; mt < 4; mt++) {
      if (which == 2) {
        int s0 = m0 + wr * 64 + mt * 16 + quad * 4;
        int bb = s0 >> 11, ss0 = s0 & 2047;
        bf16x4 o;
#pragma unroll
        for (int r = 0; r < 4; r++) o[r] = (bf16_t)(acc[mt][nt][r] + bv_);
        *(bf16x4*)(vo + ((size_t)(bb * NH + hh) * DK + dk) * SEQ + ss0) = o;
      } else {
        bf16_t* dst = (which == 0) ? qo : ko;
        float sc = (which == 0) ? QK_SCALE_LOG2 : 1.0f;
#pragma unroll
        for (int r = 0; r < 4; r++) {
          int m = m0 + wr * 64 + mt * 16 + quad * 4 + r;
          int bb = m >> 11, ss = m & 2047;
          dst[((size_t)(bb * NH + hh) * SEQ + ss) * DK + dk] =
              (bf16_t)((acc[mt][nt][r] + bv_) * sc);
        }
      }
    }
  }
}

// ---------------------------------------------------------------------------
// Residual GEMM (Wo) with FUSED LayerNorm epilogue. 32 rows x 256 cols/block.
// ---------------------------------------------------------------------------
template <int K, int LNOUT>
__global__ __launch_bounds__(256) void gemm_ln_kernel(
    const bf16_t* __restrict__ A, const bf16_t* __restrict__ BT,
    const float* __restrict__ bias, const float* __restrict__ resid,
    float* __restrict__ outf, const float* __restrict__ ls,
    const float* __restrict__ lb, bf16_t* __restrict__ outb) {
  __shared__ __align__(16) bf16_t As[2 * 2048];
  __shared__ __align__(16) bf16_t Bs[2 * 16384];
  __shared__ float2 stats[4][32];
  int tid = threadIdx.x;
  int lane = tid & 63;
  int n16 = lane & 15, quad = lane >> 4;
  int w = tid >> 6;
  int m0 = blockIdx.x * 32;

  const bf16_t* Arow = A + (size_t)m0 * K;
  f32x4 acc[2][4] = {};

  {
    int i = tid;
    int m = i >> 3, cd = i & 7, cs = cd ^ (m & 7);
    __builtin_amdgcn_global_load_lds(
        (const __attribute__((address_space(1))) unsigned int*)(Arow + (size_t)m * K + cs * 8),
        (__attribute__((address_space(3))) unsigned int*)(As + i * 8), 16, 0, 0);
    stage256(BT, Bs, tid, K, 0);
  }

  const int steps = K / 64;
#pragma unroll
  for (int s = 0; s < steps; s++) {
    int buf = s & 1;
    if (s + 1 < steps) {
      int k0 = (s + 1) * 64;
      int i = tid;
      int m = i >> 3, cd = i & 7, cs = cd ^ (m & 7);
      __builtin_amdgcn_global_load_lds(
          (const __attribute__((address_space(1))) unsigned int*)(Arow + (size_t)m * K + k0 + cs * 8),
          (__attribute__((address_space(3))) unsigned int*)(As + (buf ^ 1) * 2048 + i * 8), 16, 0, 0);
      stage256(BT, Bs + (buf ^ 1) * 16384, tid, K, k0);
    }
    __syncthreads();
    const bf16_t* a = As + buf * 2048;
    const bf16_t* b = Bs + buf * 16384;
#pragma unroll
    for (int ks = 0; ks < 2; ks++) {
      bf16x8 af[2], bfv[4];
#pragma unroll
      for (int mt = 0; mt < 2; mt++) {
        int row = mt * 16 + n16;
        int cd = (ks * 4 + quad) ^ (row & 7);
        af[mt] = *(const bf16x8*)(a + row * 64 + cd * 8);
      }
#pragma unroll
      for (int nt = 0; nt < 4; nt++) {
        int row = w * 64 + nt * 16 + n16;
        int cd = (ks * 4 + quad) ^ (row & 7);
        bfv[nt] = *(const bf16x8*)(b + row * 64 + cd * 8);
      }
#pragma unroll
      for (int mt = 0; mt < 2; mt++)
#pragma unroll
        for (int nt = 0; nt < 4; nt++)
          acc[mt][nt] = __builtin_amdgcn_mfma_f32_16x16x32_bf16(
              af[mt], bfv[nt], acc[mt][nt], 0, 0, 0);
    }
    if (s + 2 < steps) __syncthreads();
  }

  float rsum[2][4], rsq[2][4];
#pragma unroll
  for (int mt = 0; mt < 2; mt++)
#pragma unroll
    for (int r = 0; r < 4; r++) { rsum[mt][r] = 0.f; rsq[mt][r] = 0.f; }

#pragma unroll
  for (int nt = 0; nt < 4; nt++) {
    int n = w * 64 + nt * 16 + n16;
    float bv = bias[n];
#pragma unroll
    for (int mt = 0; mt < 2; mt++)
#pragma unroll
      for (int r = 0; r < 4; r++) {
        int m = m0 + mt * 16 + quad * 4 + r;
        size_t idx = (size_t)m * DIM + n;
        float hv = resid[idx] + acc[mt][nt][r] + bv;
        outf[idx] = hv;
        acc[mt][nt][r] = hv;
        rsum[mt][r] += hv;
        rsq[mt][r] += hv * hv;
      }
  }

  if (LNOUT) {
#pragma unroll
    for (int mt = 0; mt < 2; mt++)
#pragma unroll
      for (int r = 0; r < 4; r++) {
        float s_ = rsum[mt][r], q_ = rsq[mt][r];
#pragma unroll
        for (int off = 1; off < 16; off <<= 1) {
          s_ += __shfl_xor(s_, off);
          q_ += __shfl_xor(q_, off);
        }
        rsum[mt][r] = s_;
        rsq[mt][r] = q_;
      }
    if (n16 == 0) {
#pragma unroll
      for (int mt = 0; mt < 2; mt++)
#pragma unroll
        for (int r = 0; r < 4; r++)
          stats[w][mt * 16 + quad * 4 + r] = make_float2(rsum[mt][r], rsq[mt][r]);
    }
    __syncthreads();
#pragma unroll
    for (int mt = 0; mt < 2; mt++)
#pragma unroll
      for (int r = 0; r < 4; r++) {
        int lr = mt * 16 + quad * 4 + r;
        float2 t0 = stats[0][lr], t1 = stats[1][lr], t2 = stats[2][lr], t3 = stats[3][lr];
        float tot = t0.x + t1.x + t2.x + t3.x;
        float totq = t0.y + t1.y + t2.y + t3.y;
        float mean = tot * (1.0f / 256.0f);
        float var = totq * (1.0f / 256.0f) - mean * mean;
        rsum[mt][r] = mean;
        rsq[mt][r] = rsqrtf(var + 1e-5f);
      }
#pragma unroll
    for (int nt = 0; nt < 4; nt++) {
      int n = w * 64 + nt * 16 + n16;
      float sv = ls[n], bv = lb[n];
#pragma unroll
      for (int mt = 0; mt < 2; mt++)
#pragma unroll
        for (int r = 0; r < 4; r++) {
          int m = m0 + mt * 16 + quad * 4 + r;
          float x2 = (acc[mt][nt][r] - rsum[mt][r]) * rsq[mt][r] * sv + bv;
          outb[(size_t)m * DIM + n] = (bf16_t)x2;
        }
    }
  }
}

// ---------------------------------------------------------------------------
// FUSED FFN: h = resid + relu(x2@W1+b1)@W2 + b2; x2' = LN(h) (if LNOUT).
// (unchanged from R10) grid = 256, 256 threads.
// ---------------------------------------------------------------------------
template <int LNOUT>
__global__ __launch_bounds__(256) void ffn_kernel(
    const bf16_t* __restrict__ x2, const bf16_t* __restrict__ W1T,
    const bf16_t* __restrict__ W2T, const float* __restrict__ b1,
    const float* __restrict__ b2, const float* __restrict__ resid,
    float* __restrict__ outf, const float* __restrict__ ls,
    const float* __restrict__ lb, bf16_t* __restrict__ outb) {
  __shared__ __align__(16) bf16_t Wbuf[2][16384];
  __shared__ __align__(16) bf16_t H1s[32 * 512];
  __shared__ float2 stats[4][32];
  int tid = threadIdx.x;
  int lane = tid & 63;
  int n16 = lane & 15, quad = lane >> 4;
  int w = tid >> 6;
  int m0 = blockIdx.x * 32;

#pragma unroll
  for (int s = 0; s < 2; s++) {
    const bf16_t* Wsrc = W1T + (size_t)s * 256 * 256;
    f32x4 acc_a[4][2] = {};
    stage256(Wsrc, Wbuf[0], tid, 256, 0);
#pragma unroll
    for (int t = 0; t < 4; t++) {
      int buf = t & 1;
      if (t + 1 < 4) stage256(Wsrc, Wbuf[buf ^ 1], tid, 256, (t + 1) * 64);
      __syncthreads();
#pragma unroll
      for (int ks = 0; ks < 2; ks++) {
        bf16x8 af[4];
#pragma unroll
        for (int mt = 0; mt < 4; mt++) {
          int row = w * 64 + mt * 16 + n16;
          int cd = (ks * 4 + quad) ^ (row & 7);
          af[mt] = *(const bf16x8*)(Wbuf[buf] + row * 64 + cd * 8);
        }
        bf16x8 xf[2];
#pragma unroll
        for (int nt = 0; nt < 2; nt++)
          xf[nt] = *(const bf16x8*)(x2 + (size_t)(m0 + nt * 16 + n16) * 256 +
                                    t * 64 + ks * 32 + quad * 8);
#pragma unroll
        for (int mt = 0; mt < 4; mt++)
#pragma unroll
          for (int nt = 0; nt < 2; nt++)
            acc_a[mt][nt] = __builtin_amdgcn_mfma_f32_16x16x32_bf16(
                af[mt], xf[nt], acc_a[mt][nt], 0, 0, 0);
      }
      __syncthreads();
    }
#pragma unroll
    for (int mt = 0; mt < 4; mt++) {
      int hid0 = s * 256 + w * 64 + mt * 16 + quad * 4;
      float b1v0 = b1[hid0], b1v1 = b1[hid0 + 1], b1v2 = b1[hid0 + 2], b1v3 = b1[hid0 + 3];
      int c = hid0 >> 3;
      int off4 = (quad & 1) * 4;
#pragma unroll
      for (int nt = 0; nt < 2; nt++) {
        int tok = nt * 16 + n16;
        bf16x4 o = {(bf16_t)fmaxf(acc_a[mt][nt][0] + b1v0, 0.0f),
                    (bf16_t)fmaxf(acc_a[mt][nt][1] + b1v1, 0.0f),
                    (bf16_t)fmaxf(acc_a[mt][nt][2] + b1v2, 0.0f),
                    (bf16_t)fmaxf(acc_a[mt][nt][3] + b1v3, 0.0f)};
        int cs = c ^ (n16 & 7);
        *(bf16x4*)(H1s + tok * 512 + cs * 8 + off4) = o;
      }
    }
  }
  __syncthreads();

  f32x4 acc[2][4] = {};
  stage256(W2T, Wbuf[0], tid, 512, 0);
#pragma unroll
  for (int s = 0; s < 8; s++) {
    int buf = s & 1;
    if (s + 1 < 8) stage256(W2T, Wbuf[buf ^ 1], tid, 512, (s + 1) * 64);
    __syncthreads();
#pragma unroll
    for (int ks = 0; ks < 2; ks++) {
      bf16x8 af2[2];
#pragma unroll
      for (int mt = 0; mt < 2; mt++) {
        int tok = mt * 16 + n16;
        int g = (s * 8 + ks * 4 + quad) ^ (n16 & 7);
        af2[mt] = *(const bf16x8*)(H1s + tok * 512 + g * 8);
      }
      bf16x8 bf2[4];
#pragma unroll
      for (int nt = 0; nt < 4; nt++) {
        int rowb = w * 64 + nt * 16 + n16;
        int cd = (ks * 4 + quad) ^ (rowb & 7);
        bf2[nt] = *(const bf16x8*)(Wbuf[buf] + rowb * 64 + cd * 8);
      }
#pragma unroll
      for (int mt = 0; mt < 2; mt++)
#pragma unroll
        for (int nt = 0; nt < 4; nt++)
          acc[mt][nt] = __builtin_amdgcn_mfma_f32_16x16x32_bf16(
              af2[mt], bf2[nt], acc[mt][nt], 0, 0, 0);
    }
    __syncthreads();
  }

  float rsum[2][4], rsq[2][4];
#pragma unroll
  for (int mt = 0; mt < 2; mt++)
#pragma unroll
    for (int r = 0; r < 4; r++) { rsum[mt][r] = 0.f; rsq[mt][r] = 0.f; }

#pragma unroll
  for (int nt = 0; nt < 4; nt++) {
    int n = w * 64 + nt * 16 + n16;
    float bv = b2[n];
#pragma unroll
    for (int mt = 0; mt < 2; mt++)
#pragma unroll
      for (int r = 0; r < 4; r++) {
        int m = m0 + mt * 16 + quad * 4 + r;
        size_t idx = (size_t)m * DIM + n;
        float hv = resid[idx] + acc[mt][nt][r] + bv;
        outf[idx] = hv;
        acc[mt][nt][r] = hv;
        rsum[mt][r] += hv;
        rsq[mt][r] += hv * hv;
      }
  }

  if (LNOUT) {
#pragma unroll
    for (int mt = 0; mt < 2; mt++)
#pragma unroll
      for (int r = 0; r < 4; r++) {
        float s_ = rsum[mt][r], q_ = rsq[mt][r];
#pragma unroll
        for (int off = 1; off < 16; off <<= 1) {
          s_ += __shfl_xor(s_, off);
          q_ += __shfl_xor(q_, off);
        }
        rsum[mt][r] = s_;
        rsq[mt][r] = q_;
      }
    if (n16 == 0) {
#pragma unroll
      for (int mt = 0; mt < 2; mt++)
#pragma unroll
        for (int r = 0; r < 4; r++)
          stats[w][mt * 16 + quad * 4 + r] = make_float2(rsum[mt][r], rsq[mt][r]);
    }
    __syncthreads();
#pragma unroll
    for (int mt = 0; mt < 2; mt++)
#pragma unroll
      for (int r = 0; r < 4; r++) {
        int lr = mt * 16 + quad * 4 + r;
        float2 t0 = stats[0][lr], t1 = stats[1][lr], t2 = stats[2][lr], t3 = stats[3][lr];
        float tot = t0.x + t1.x + t2.x + t3.x;
        float totq = t0.y + t1.y + t2.y + t3.y;
        float mean = tot * (1.0f / 256.0f);
        float var = totq * (1.0f / 256.0f) - mean * mean;
        rsum[mt][r] = mean;
        rsq[mt][r] = rsqrtf(var + 1e-5f);
      }
#pragma unroll
    for (int nt = 0; nt < 4; nt++) {
      int n = w * 64 + nt * 16 + n16;
      float sv = ls[n], bv = lb[n];
#pragma unroll
      for (int mt = 0; mt < 2; mt++)
#pragma unroll
        for (int r = 0; r < 4; r++) {
          int m = m0 + mt * 16 + quad * 4 + r;
          float x2v = (acc[mt][nt][r] - rsum[mt][r]) * rsq[mt][r] * sv + bv;
          outb[(size_t)m * DIM + n] = (bf16_t)x2v;
        }
    }
  }
}

// ---------------------------------------------------------------------------
// Flash attention v9: KV-split x2 on the pipelined flash8 body. No max-shift
// -> exact partial sums; block handles 64 q x 1024 keys (16 tiles).
// grid (32 bh, 32 qblk, 2 part) = 2048 blocks -> 8 blocks/CU = 4 waves/SIMD
// (launch_bounds(128,4)). Writes unnormalized f32 Opart + lpart.
// ---------------------------------------------------------------------------
__global__ __launch_bounds__(128, 4) void flash9_kernel(
    const bf16_t* __restrict__ Q, const bf16_t* __restrict__ K,
    const bf16_t* __restrict__ VT, float* __restrict__ Opart,
    float* __restrict__ lpart) {
  __shared__ __align__(16) bf16_t Plds[2][2][32][72];
  int bh = blockIdx.x;
  int q0 = blockIdx.y * 64;
  int part = blockIdx.z;
  int w = threadIdx.x >> 6;
  int lane = threadIdx.x & 63;
  int n16 = lane & 15;
  int quad = lane >> 4;

  const bf16_t* Qb = Q + (size_t)bh * SEQ * DK;
  const bf16_t* Kb = K + (size_t)bh * SEQ * DK + (size_t)part * 1024 * DK;
  const bf16_t* Vb = VT + (size_t)bh * DK * SEQ + part * 1024;
  int qr0 = q0 + w * 32;

  bf16x8 qfrag[2];
#pragma unroll
  for (int qg = 0; qg < 2; qg++)
    qfrag[qg] = *(const bf16x8*)(Qb + (size_t)(qr0 + qg * 16 + n16) * DK + quad * 8);

  bf16_t one = (bf16_t)1.0f;
  bf16x8 ones = {one, one, one, one, one, one, one, one};

  f32x4 oacc[2][2] = {};
  f32x4 lacc[2] = {};

  // prologue: P_0 into buf 0
  {
    bf16x8 kf0[4];
#pragma unroll
    for (int t = 0; t < 4; t++)
      kf0[t] = *(const bf16x8*)(Kb + (size_t)(t * 16 + n16) * DK + quad * 8);
#pragma unroll
    for (int qg = 0; qg < 2; qg++)
#pragma unroll
      for (int t = 0; t < 4; t++) {
        f32x4 sc = __builtin_amdgcn_mfma_f32_16x16x32_bf16(
            kf0[t], qfrag[qg], (f32x4){0.f, 0.f, 0.f, 0.f}, 0, 0, 0);
        bf16x4 pf;
#pragma unroll
        for (int r = 0; r < 4; r++) pf[r] = (bf16_t)FAST_EXP2(sc[r]);
        *(bf16x4*)&Plds[0][w][qg * 16 + n16][t * 16 + quad * 4] = pf;
      }
  }
  bf16x8 kfS[4], vfP[2][2];
#pragma unroll
  for (int t = 0; t < 4; t++)
    kfS[t] = *(const bf16x8*)(Kb + (size_t)(64 + t * 16 + n16) * DK + quad * 8);
#pragma unroll
  for (int c = 0; c < 2; c++) {
    vfP[c][0] = *(const bf16x8*)(Vb + (size_t)n16 * SEQ + c * 32 + quad * 8);
    vfP[c][1] = *(const bf16x8*)(Vb + (size_t)(16 + n16) * SEQ + c * 32 + quad * 8);
  }

#pragma unroll 2
  for (int i = 0; i < 16; i++) {
    int buf = i & 1;
    bf16x8 pf8[2][2];
#pragma unroll
    for (int qg = 0; qg < 2; qg++)
#pragma unroll
      for (int c = 0; c < 2; c++)
        pf8[qg][c] = *(const bf16x8*)&Plds[buf][w][qg * 16 + n16][c * 32 + quad * 8];
    bf16x8 kfN[4], vfN[2][2];
    if (i + 2 < 16) {
      int kb = (i + 2) * 64;
#pragma unroll
      for (int t = 0; t < 4; t++)
        kfN[t] = *(const bf16x8*)(Kb + (size_t)(kb + t * 16 + n16) * DK + quad * 8);
    }
    if (i + 1 < 16) {
      int kb = (i + 1) * 64;
#pragma unroll
      for (int c = 0; c < 2; c++) {
        vfN[c][0] = *(const bf16x8*)(Vb + (size_t)n16 * SEQ + kb + c * 32 + quad * 8);
        vfN[c][1] = *(const bf16x8*)(Vb + (size_t)(16 + n16) * SEQ + kb + c * 32 + quad * 8);
      }
    }
    if (i + 1 < 16) {
#pragma unroll
      for (int qg = 0; qg < 2; qg++)
#pragma unroll
        for (int t = 0; t < 4; t++) {
          f32x4 sc = __builtin_amdgcn_mfma_f32_16x16x32_bf16(
              kfS[t], qfrag[qg], (f32x4){0.f, 0.f, 0.f, 0.f}, 0, 0, 0);
          bf16x4 pf;
#pragma unroll
          for (int r = 0; r < 4; r++) pf[r] = (bf16_t)FAST_EXP2(sc[r]);
          *(bf16x4*)&Plds[buf ^ 1][w][qg * 16 + n16][t * 16 + quad * 4] = pf;
        }
    }
#pragma unroll
    for (int qg = 0; qg < 2; qg++)
#pragma unroll
      for (int c = 0; c < 2; c++) {
        lacc[qg] = __builtin_amdgcn_mfma_f32_16x16x32_bf16(pf8[qg][c], ones, lacc[qg], 0, 0, 0);
        oacc[qg][0] = __builtin_amdgcn_mfma_f32_16x16x32_bf16(pf8[qg][c], vfP[c][0], oacc[qg][0], 0, 0, 0);
        oacc[qg][1] = __builtin_amdgcn_mfma_f32_16x16x32_bf16(pf8[qg][c], vfP[c][1], oacc[qg][1], 0, 0, 0);
      }
    if (i + 2 < 16) {
#pragma unroll
      for (int t = 0; t < 4; t++) kfS[t] = kfN[t];
    }
    if (i + 1 < 16) {
#pragma unroll
      for (int c = 0; c < 2; c++) {
        vfP[c][0] = vfN[c][0];
        vfP[c][1] = vfN[c][1];
      }
    }
  }

  size_t rowbase = (size_t)part * 65536 + (size_t)bh * SEQ;
#pragma unroll
  for (int qg = 0; qg < 2; qg++) {
#pragma unroll
    for (int r = 0; r < 4; r++) {
      int row = qr0 + qg * 16 + quad * 4 + r;
      float* op = Opart + (rowbase + row) * 32;
      op[n16] = oacc[qg][0][r];
      op[16 + n16] = oacc[qg][1][r];
      if (n16 == 0) lpart[rowbase + row] = lacc[qg][r];
    }
  }
}

// ---------------------------------------------------------------------------
// Combine KV-split partials: O = (O0+O1)/(l0+l1) -> bf16 [B,S,D].
// grid 2048 x 256; one float4 (4 dk) per thread, fully coalesced.
// ---------------------------------------------------------------------------
__global__ __launch_bounds__(256) void combine_kernel(
    const float* __restrict__ Opart, const float* __restrict__ lpart,
    bf16_t* __restrict__ OB) {
  int g = blockIdx.x * 256 + threadIdx.x;
  int row = g >> 3;          // bh*SEQ + s
  int dk0 = (g & 7) * 4;
  float4 o0 = *(const float4*)(Opart + (size_t)row * 32 + dk0);
  float4 o1 = *(const float4*)(Opart + (size_t)(65536 + row) * 32 + dk0);
  float linv = 1.0f / (lpart[row] + lpart[65536 + row]);
  int bh = row >> 11, s = row & 2047;
  int bb = bh >> 3, hh = bh & 7;
  bf16x4 o = {(bf16_t)((o0.x + o1.x) * linv), (bf16_t)((o0.y + o1.y) * linv),
              (bf16_t)((o0.z + o1.z) * linv), (bf16_t)((o0.w + o1.w) * linv)};
  *(bf16x4*)(OB + ((size_t)(bb * SEQ + s)) * DIM + hh * DK + dk0) = o;
}

// ---------------------------------------------------------------------------
extern "C" void kernel_launch(void* const* d_in, const int* in_sizes, int n_in,
                              void* d_out, int out_size, void* d_ws, size_t ws_size,
                              hipStream_t stream) {
  const float* x     = (const float*)d_in[0];
  const float* ln0_s = (const float*)d_in[1];
  const float* ln0_b = (const float*)d_in[2];
  const float* ln1_s = (const float*)d_in[3];
  const float* ln1_b = (const float*)d_in[4];
  const float* ln2_s = (const float*)d_in[5];
  const float* ln2_b = (const float*)d_in[6];
  const float* wq = (const float*)d_in[7];
  const float* bq = (const float*)d_in[8];
  const float* wk = (const float*)d_in[9];
  const float* bk = (const float*)d_in[10];
  const float* wv = (const float*)d_in[11];
  const float* bv = (const float*)d_in[12];
  const float* wo = (const float*)d_in[13];
  const float* bo = (const float*)d_in[14];
  const float* w1 = (const float*)d_in[15];
  const float* b1 = (const float*)d_in[16];
  const float* w2 = (const float*)d_in[17];
  const float* b2 = (const float*)d_in[18];

  float* out = (float*)d_out;  // h (fp32 residual stream) lives here
  const size_t ACT = (size_t)8192 * DIM;  // 2,097,152

  bf16_t* wsb = (bf16_t*)d_ws;
  bf16_t* x2b = wsb;                 // ACT
  bf16_t* obf = x2b + ACT;           // ACT
  bf16_t* qbf = obf + ACT;           // ACT
  bf16_t* kbf = qbf + ACT;           // ACT
  bf16_t* vbf = kbf + ACT;           // ACT (transposed [B,H,DK,S])
  bf16_t* WqT = vbf + ACT;           // 4 x 65536
  bf16_t* WkT = WqT + 4 * 65536;
  bf16_t* WvT = WkT + 4 * 65536;
  bf16_t* WoT = WvT + 4 * 65536;
  bf16_t* W1T = WoT + 4 * 65536;     // 4 x 131072
  bf16_t* W2T = W1T + 4 * 131072;    // 4 x 131072
  float* Opart = (float*)(W2T + 4 * 131072);      // 2 x 65536 x 32 f32
  float* lpart = Opart + (size_t)2 * 65536 * 32;  // 2 x 65536 f32

  dim3 blk(256);
  dim3 blkF(128);
  dim3 gLN(2048);
  dim3 gRow(256);
  dim3 gQKV(6, 64);
  dim3 gAtt(32, 32, 2);
  dim3 gComb(2048);

  wtrans_all_kernel<<<dim3(512), blk, 0, stream>>>(wq, wk, wv, wo, w1, w2,
                                                   WqT, WkT, WvT, WoT, W1T, W2T);

  // h = LN(x, ln0); x2 = LN(h, ln1[0])
  ln_double_kernel<<<gLN, blk, 0, stream>>>(x, ln0_s, ln0_b, ln1_s, ln1_b, out, x2b);

  for (int l = 0; l < 4; l++) {
    bf16_t* WqTl = WqT + (size_t)l * 65536;
    bf16_t* WkTl = WkT + (size_t)l * 65536;
    bf16_t* WvTl = WvT + (size_t)l * 65536;
    bf16_t* WoTl = WoT + (size_t)l * 65536;
    bf16_t* W1Tl = W1T + (size_t)l * 131072;
    bf16_t* W2Tl = W2T + (size_t)l * 131072;

    // fused q,k,v projections
    qkv9_kernel<<<gQKV, blk, 0, stream>>>(x2b, WqTl, WkTl, WvTl,
                                          bq + l * DIM, bk + l * DIM, bv + l * DIM,
                                          qbf, kbf, vbf);
    // attention: KV-split partials + combine
    flash9_kernel<<<gAtt, blkF, 0, stream>>>(qbf, kbf, vbf, Opart, lpart);
    combine_kernel<<<gComb, blk, 0, stream>>>(Opart, lpart, obf);
    // h = h + o @ Wo + bo;  x2 = LN(h, ln2)   [fused]
    gemm_ln_kernel<256, 1><<<gRow, blk, 0, stream>>>(
        obf, WoTl, bo + l * DIM, out, out, ln2_s + l * DIM, ln2_b + l * DIM, x2b);
    // h = h + relu(x2@W1+b1)@W2 + b2;  x2 = LN(h, ln1[l+1])  [fused FFN]
    if (l < 3) {
      ffn_kernel<1><<<gRow, blk, 0, stream>>>(
          x2b, W1Tl, W2Tl, b1 + l * FF, b2 + l * DIM, out, out,
          ln1_s + (l + 1) * DIM, ln1_b + (l + 1) * DIM, x2b);
    } else {
      ffn_kernel<0><<<gRow, blk, 0, stream>>>(
          x2b, W1Tl, W2Tl, b1 + l * FF, b2 + l * DIM, out, out,
          nullptr, nullptr, nullptr);
    }
  }
}

// Round 13
// 423.421 us; speedup vs baseline: 1.2831x; 1.2831x over previous
//
#include <hip/hip_runtime.h>
#include <hip/hip_bf16.h>
#include <math.h>

// Problem constants: B=4, S=2048, D=256, H=8, DK=32, L=4, FF=512
#define SEQ 2048
#define DIM 256
#define NH 8
#define DK 32
#define FF 512

typedef __bf16 bf16_t;
typedef bf16_t bf16x8 __attribute__((ext_vector_type(8)));
typedef bf16_t bf16x4 __attribute__((ext_vector_type(4)));
typedef float f32x4 __attribute__((ext_vector_type(4)));

// Q pre-scaled by (1/sqrt(DK)) * log2(e); softmax exp becomes v_exp_f32 (2^x).
#define QK_SCALE_LOG2 0.25503226632462494f
#if __has_builtin(__builtin_amdgcn_exp2f)
#define FAST_EXP2(x) __builtin_amdgcn_exp2f(x)
#else
#define FAST_EXP2(x) __expf((x) * 0.6931471805599453f)
#endif

// ---------------------------------------------------------------------------
// Double LayerNorm (start): h = LN(x,ln0); x2 = LN(h,ln1[0]).
// ---------------------------------------------------------------------------
__global__ __launch_bounds__(256) void ln_double_kernel(
    const float* __restrict__ x, const float* __restrict__ s0,
    const float* __restrict__ b0, const float* __restrict__ s1,
    const float* __restrict__ b1, float* __restrict__ outf,
    bf16_t* __restrict__ outb) {
  int wave = threadIdx.x >> 6;
  int lane = threadIdx.x & 63;
  int row = blockIdx.x * 4 + wave;
  float4 xv = *(const float4*)(x + (size_t)row * DIM + lane * 4);
  float sum = xv.x + xv.y + xv.z + xv.w;
  float sq = xv.x * xv.x + xv.y * xv.y + xv.z * xv.z + xv.w * xv.w;
#pragma unroll
  for (int off = 1; off < 64; off <<= 1) {
    sum += __shfl_xor(sum, off);
    sq += __shfl_xor(sq, off);
  }
  float mean = sum * (1.0f / 256.0f);
  float var = sq * (1.0f / 256.0f) - mean * mean;
  float inv = rsqrtf(var + 1e-5f);
  float4 sv = *(const float4*)(s0 + lane * 4);
  float4 bv = *(const float4*)(b0 + lane * 4);
  float4 h;
  h.x = (xv.x - mean) * inv * sv.x + bv.x;
  h.y = (xv.y - mean) * inv * sv.y + bv.y;
  h.z = (xv.z - mean) * inv * sv.z + bv.z;
  h.w = (xv.w - mean) * inv * sv.w + bv.w;
  *(float4*)(outf + (size_t)row * DIM + lane * 4) = h;
  float sum2 = h.x + h.y + h.z + h.w;
  float sq2 = h.x * h.x + h.y * h.y + h.z * h.z + h.w * h.w;
#pragma unroll
  for (int off = 1; off < 64; off <<= 1) {
    sum2 += __shfl_xor(sum2, off);
    sq2 += __shfl_xor(sq2, off);
  }
  float mean2 = sum2 * (1.0f / 256.0f);
  float var2 = sq2 * (1.0f / 256.0f) - mean2 * mean2;
  float inv2 = rsqrtf(var2 + 1e-5f);
  float4 s1v = *(const float4*)(s1 + lane * 4);
  float4 b1v = *(const float4*)(b1 + lane * 4);
  bf16x4 ob = {(bf16_t)((h.x - mean2) * inv2 * s1v.x + b1v.x),
               (bf16_t)((h.y - mean2) * inv2 * s1v.y + b1v.y),
               (bf16_t)((h.z - mean2) * inv2 * s1v.z + b1v.z),
               (bf16_t)((h.w - mean2) * inv2 * s1v.w + b1v.w)};
  *(bf16x4*)(outb + (size_t)row * DIM + lane * 4) = ob;
}

// ---------------------------------------------------------------------------
// All-weights transpose+convert in ONE dispatch (512 blocks).
// ---------------------------------------------------------------------------
__global__ __launch_bounds__(256) void wtrans_all_kernel(
    const float* __restrict__ wq, const float* __restrict__ wk,
    const float* __restrict__ wv, const float* __restrict__ wo,
    const float* __restrict__ w1, const float* __restrict__ w2,
    bf16_t* __restrict__ WqT, bf16_t* __restrict__ WkT,
    bf16_t* __restrict__ WvT, bf16_t* __restrict__ WoT,
    bf16_t* __restrict__ W1T, bf16_t* __restrict__ W2T) {
  __shared__ float tile[64][65];
  int idx = blockIdx.x;
  int layer = idx >> 7;
  int r = idx & 127;
  const float* src;
  bf16_t* dst;
  int N, k0, n0;
  if (r < 64) {
    int which = r >> 4, t = r & 15;
    N = 256;
    k0 = (t & 3) * 64;
    n0 = (t >> 2) * 64;
    src = (which == 0 ? wq : which == 1 ? wk : which == 2 ? wv : wo) + (size_t)layer * 65536;
    dst = (which == 0 ? WqT : which == 1 ? WkT : which == 2 ? WvT : WoT) + (size_t)layer * 65536;
  } else if (r < 96) {
    int t = r - 64;
    N = 512;
    k0 = (t & 3) * 64;
    n0 = (t >> 2) * 64;
    src = w1 + (size_t)layer * 131072;
    dst = W1T + (size_t)layer * 131072;
  } else {
    int t = r - 96;
    N = 256;
    k0 = (t & 7) * 64;
    n0 = (t >> 3) * 64;
    src = w2 + (size_t)layer * 131072;
    dst = W2T + (size_t)layer * 131072;
  }
  int K = (r >= 96) ? 512 : 256;

  int tr = threadIdx.x >> 4;
  int tc4 = (threadIdx.x & 15) * 4;
#pragma unroll
  for (int i = 0; i < 4; i++) {
    int kl = i * 16 + tr;
    float4 v = *(const float4*)(src + (size_t)(k0 + kl) * N + n0 + tc4);
    tile[kl][tc4 + 0] = v.x; tile[kl][tc4 + 1] = v.y;
    tile[kl][tc4 + 2] = v.z; tile[kl][tc4 + 3] = v.w;
  }
  __syncthreads();
#pragma unroll
  for (int i = 0; i < 4; i++) {
    int nl = i * 16 + tr;
    bf16x4 o = {(bf16_t)tile[tc4 + 0][nl], (bf16_t)tile[tc4 + 1][nl],
                (bf16_t)tile[tc4 + 2][nl], (bf16_t)tile[tc4 + 3][nl]};
    *(bf16x4*)(dst + (size_t)(n0 + nl) * K + k0 + tc4) = o;
  }
}

// ---------------------------------------------------------------------------
// Staging helpers (global_load_lds width=16, XOR chunk swizzle on source).
// ---------------------------------------------------------------------------
__device__ __forceinline__ void stage128(const bf16_t* __restrict__ src,
                                         bf16_t* dst, int tid, int ldk, int k0) {
#pragma unroll
  for (int u = 0; u < 4; u++) {
    int i = u * 256 + tid;
    int m = i >> 3, cd = i & 7, cs = cd ^ (m & 7);
    __builtin_amdgcn_global_load_lds(
        (const __attribute__((address_space(1))) unsigned int*)(src + (size_t)m * ldk + k0 + cs * 8),
        (__attribute__((address_space(3))) unsigned int*)(dst + i * 8), 16, 0, 0);
  }
}

// stages 256 rows x 64 k (32 KB)
__device__ __forceinline__ void stage256(const bf16_t* __restrict__ src,
                                         bf16_t* dst, int tid, int ldk, int k0) {
#pragma unroll
  for (int u = 0; u < 8; u++) {
    int j = u * 256 + tid;
    int m = j >> 3, cd = j & 7, cs = cd ^ (m & 7);
    __builtin_amdgcn_global_load_lds(
        (const __attribute__((address_space(1))) unsigned int*)(src + (size_t)m * ldk + k0 + cs * 8),
        (__attribute__((address_space(3))) unsigned int*)(dst + j * 8), 16, 0, 0);
  }
}

__device__ __forceinline__ void compute128(const bf16_t* As, const bf16_t* Bs,
                                           int wr, int wc, int n16, int quad,
                                           f32x4 (&acc)[4][4]) {
#pragma unroll
  for (int ks = 0; ks < 2; ks++) {
    bf16x8 af[4], bf[4];
#pragma unroll
    for (int mt = 0; mt < 4; mt++) {
      int row = wr * 64 + mt * 16 + n16;
      int cd = (ks * 4 + quad) ^ (row & 7);
      af[mt] = *(const bf16x8*)(As + row * 64 + cd * 8);
    }
#pragma unroll
    for (int nt = 0; nt < 4; nt++) {
      int row = wc * 64 + nt * 16 + n16;
      int cd = (ks * 4 + quad) ^ (row & 7);
      bf[nt] = *(const bf16x8*)(Bs + row * 64 + cd * 8);
    }
#pragma unroll
    for (int mt = 0; mt < 4; mt++)
#pragma unroll
      for (int nt = 0; nt < 4; nt++)
        acc[mt][nt] = __builtin_amdgcn_mfma_f32_16x16x32_bf16(
            af[mt], bf[nt], acc[mt][nt], 0, 0, 0);
  }
}

template <int K>
__device__ __forceinline__ void gemm9_body(
    const bf16_t* __restrict__ A, const bf16_t* __restrict__ BT,
    int m0, int n0, int tid, bf16_t* As, bf16_t* Bs, f32x4 (&acc)[4][4]) {
  int lane = tid & 63;
  int n16 = lane & 15, quad = lane >> 4;
  int w = tid >> 6;
  int wr = w >> 1, wc = w & 1;
  const bf16_t* Arow = A + (size_t)m0 * K;
  const bf16_t* Brow = BT + (size_t)n0 * K;

  stage128(Arow, As, tid, K, 0);
  stage128(Brow, Bs, tid, K, 0);

  const int steps = K / 64;
#pragma unroll
  for (int s = 0; s < steps; s++) {
    int buf = s & 1;
    if (s + 1 < steps) {
      stage128(Arow, As + (buf ^ 1) * 8192, tid, K, (s + 1) * 64);
      stage128(Brow, Bs + (buf ^ 1) * 8192, tid, K, (s + 1) * 64);
    }
    __syncthreads();
    compute128(As + buf * 8192, Bs + buf * 8192, wr, wc, n16, quad, acc);
    if (s + 2 < steps) __syncthreads();
  }
}

// ---------------------------------------------------------------------------
// Fused QKV projection (128x128 body): grid (6, 64).
// ---------------------------------------------------------------------------
__global__ __launch_bounds__(256) void qkv9_kernel(
    const bf16_t* __restrict__ A,
    const bf16_t* __restrict__ WqT, const bf16_t* __restrict__ WkT,
    const bf16_t* __restrict__ WvT,
    const float* __restrict__ bq, const float* __restrict__ bk,
    const float* __restrict__ bv,
    bf16_t* __restrict__ qo, bf16_t* __restrict__ ko,
    bf16_t* __restrict__ vo) {
  __shared__ __align__(16) bf16_t As[2 * 8192];
  __shared__ __align__(16) bf16_t Bs[2 * 8192];
  int which = blockIdx.x >> 1;
  int nblk = blockIdx.x & 1;
  const bf16_t* BT = (which == 0) ? WqT : (which == 1) ? WkT : WvT;
  const float* bias = (which == 0) ? bq : (which == 1) ? bk : bv;

  int tid = threadIdx.x;
  int lane = tid & 63;
  int n16 = lane & 15, quad = lane >> 4;
  int w = tid >> 6;
  int wr = w >> 1, wc = w & 1;
  int m0 = blockIdx.y * 128, n0 = nblk * 128;
  f32x4 acc[4][4] = {};
  gemm9_body<256>(A, BT, m0, n0, tid, As, Bs, acc);

#pragma unroll
  for (int nt = 0; nt < 4; nt++) {
    int n = n0 + wc * 64 + nt * 16 + n16;
    float bv_ = bias[n];
    int hh = n >> 5, dk = n & 31;
#pragma unroll
    for (int mt = 0; mt < 4; mt++) {
      if (which == 2) {
        int s0 = m0 + wr * 64 + mt * 16 + quad * 4;
        int bb = s0 >> 11, ss0 = s0 & 2047;
        bf16x4 o;
#pragma unroll
        for (int r = 0; r < 4; r++) o[r] = (bf16_t)(acc[mt][nt][r] + bv_);
        *(bf16x4*)(vo + ((size_t)(bb * NH + hh) * DK + dk) * SEQ + ss0) = o;
      } else {
        bf16_t* dst = (which == 0) ? qo : ko;
        float sc = (which == 0) ? QK_SCALE_LOG2 : 1.0f;
#pragma unroll
        for (int r = 0; r < 4; r++) {
          int m = m0 + wr * 64 + mt * 16 + quad * 4 + r;
          int bb = m >> 11, ss = m & 2047;
          dst[((size_t)(bb * NH + hh) * SEQ + ss) * DK + dk] =
              (bf16_t)((acc[mt][nt][r] + bv_) * sc);
        }
      }
    }
  }
}

// ---------------------------------------------------------------------------
// FUSED LAYER TAIL: per 32 token rows (grid 256, 256 threads):
//   phase 0: h = h_prev + o@Wo + bo            (h kept in REGISTERS)
//            x2m = LN(h, ln2)                  -> LDS X2s (padded 264)
//   phase A: h1 = relu(x2m @ W1 + b1)          -> LDS H1s
//   phase B: h' = h + h1 @ W2 + b2             -> outf (global, fp32)
//            if LNOUT: x2 = LN(h', ln1_next)   -> outb (global, bf16)
// Removes the gemm_ln/ffn dispatch boundary and the x2/h global round-trips.
// LDS: Wbuf 64K + H1s 32K (phase0 As aliases its first 8K) + X2s 16.5K.
// ---------------------------------------------------------------------------
template <int LNOUT>
__global__ __launch_bounds__(256) void tail_kernel(
    const bf16_t* __restrict__ O, const bf16_t* __restrict__ WoT,
    const float* __restrict__ bo, const bf16_t* __restrict__ W1T,
    const bf16_t* __restrict__ W2T, const float* __restrict__ b1,
    const float* __restrict__ b2, const float* __restrict__ ls2,
    const float* __restrict__ lb2, float* __restrict__ outf,
    const float* __restrict__ ls1n, const float* __restrict__ lb1n,
    bf16_t* __restrict__ outb) {
  __shared__ __align__(16) bf16_t Wbuf[2][16384];  // 64 KB
  __shared__ __align__(16) bf16_t H1s[32 * 512];   // 32 KB (first 8 KB = phase0 As)
  __shared__ __align__(16) bf16_t X2s[32 * 264];   // 16.5 KB, padded rows
  __shared__ float2 stats[4][32];
  int tid = threadIdx.x;
  int lane = tid & 63;
  int n16 = lane & 15, quad = lane >> 4;
  int w = tid >> 6;
  int m0 = blockIdx.x * 32;
  bf16_t* As = H1s;  // alias: phase-0 A staging (8 KB), dead before H1s written

  // ---------------- Phase 0: h = h_prev + O @ Wo + bo ----------------
  f32x4 hreg[2][4] = {};
  {
    const bf16_t* Arow = O + (size_t)m0 * 256;
    {
      int i = tid;
      int m = i >> 3, cd = i & 7, cs = cd ^ (m & 7);
      __builtin_amdgcn_global_load_lds(
          (const __attribute__((address_space(1))) unsigned int*)(Arow + (size_t)m * 256 + cs * 8),
          (__attribute__((address_space(3))) unsigned int*)(As + i * 8), 16, 0, 0);
      stage256(WoT, Wbuf[0], tid, 256, 0);
    }
#pragma unroll
    for (int s = 0; s < 4; s++) {
      int buf = s & 1;
      if (s + 1 < 4) {
        int k0 = (s + 1) * 64;
        int i = tid;
        int m = i >> 3, cd = i & 7, cs = cd ^ (m & 7);
        __builtin_amdgcn_global_load_lds(
            (const __attribute__((address_space(1))) unsigned int*)(Arow + (size_t)m * 256 + k0 + cs * 8),
            (__attribute__((address_space(3))) unsigned int*)(As + (buf ^ 1) * 2048 + i * 8), 16, 0, 0);
        stage256(WoT, Wbuf[buf ^ 1], tid, 256, k0);
      }
      __syncthreads();
      const bf16_t* a = As + buf * 2048;
      const bf16_t* b = Wbuf[buf];
#pragma unroll
      for (int ks = 0; ks < 2; ks++) {
        bf16x8 af[2], bfv[4];
#pragma unroll
        for (int mt = 0; mt < 2; mt++) {
          int row = mt * 16 + n16;
          int cd = (ks * 4 + quad) ^ (row & 7);
          af[mt] = *(const bf16x8*)(a + row * 64 + cd * 8);
        }
#pragma unroll
        for (int nt = 0; nt < 4; nt++) {
          int row = w * 64 + nt * 16 + n16;
          int cd = (ks * 4 + quad) ^ (row & 7);
          bfv[nt] = *(const bf16x8*)(b + row * 64 + cd * 8);
        }
#pragma unroll
        for (int mt = 0; mt < 2; mt++)
#pragma unroll
          for (int nt = 0; nt < 4; nt++)
            hreg[mt][nt] = __builtin_amdgcn_mfma_f32_16x16x32_bf16(
                af[mt], bfv[nt], hreg[mt][nt], 0, 0, 0);
      }
      __syncthreads();
    }
  }

  // residual add (h_prev from outf) + LN stats
  float rsum[2][4], rsq[2][4];
#pragma unroll
  for (int mt = 0; mt < 2; mt++)
#pragma unroll
    for (int r = 0; r < 4; r++) { rsum[mt][r] = 0.f; rsq[mt][r] = 0.f; }
#pragma unroll
  for (int nt = 0; nt < 4; nt++) {
    int n = w * 64 + nt * 16 + n16;
    float bv = bo[n];
#pragma unroll
    for (int mt = 0; mt < 2; mt++)
#pragma unroll
      for (int r = 0; r < 4; r++) {
        int m = m0 + mt * 16 + quad * 4 + r;
        float hv = outf[(size_t)m * DIM + n] + hreg[mt][nt][r] + bv;
        hreg[mt][nt][r] = hv;
        rsum[mt][r] += hv;
        rsq[mt][r] += hv * hv;
      }
  }
  // cross-lane + cross-wave LN stats
#pragma unroll
  for (int mt = 0; mt < 2; mt++)
#pragma unroll
    for (int r = 0; r < 4; r++) {
      float s_ = rsum[mt][r], q_ = rsq[mt][r];
#pragma unroll
      for (int off = 1; off < 16; off <<= 1) {
        s_ += __shfl_xor(s_, off);
        q_ += __shfl_xor(q_, off);
      }
      rsum[mt][r] = s_;
      rsq[mt][r] = q_;
    }
  if (n16 == 0) {
#pragma unroll
    for (int mt = 0; mt < 2; mt++)
#pragma unroll
      for (int r = 0; r < 4; r++)
        stats[w][mt * 16 + quad * 4 + r] = make_float2(rsum[mt][r], rsq[mt][r]);
  }
  __syncthreads();
#pragma unroll
  for (int mt = 0; mt < 2; mt++)
#pragma unroll
    for (int r = 0; r < 4; r++) {
      int lr = mt * 16 + quad * 4 + r;
      float2 t0 = stats[0][lr], t1 = stats[1][lr], t2 = stats[2][lr], t3 = stats[3][lr];
      float tot = t0.x + t1.x + t2.x + t3.x;
      float totq = t0.y + t1.y + t2.y + t3.y;
      float mean = tot * (1.0f / 256.0f);
      float var = totq * (1.0f / 256.0f) - mean * mean;
      rsum[mt][r] = mean;
      rsq[mt][r] = rsqrtf(var + 1e-5f);
    }
  // x2m = LN(h, ln2) -> X2s (scalar stores, once per block; padded rows)
#pragma unroll
  for (int nt = 0; nt < 4; nt++) {
    int n = w * 64 + nt * 16 + n16;
    float sv = ls2[n], bv = lb2[n];
#pragma unroll
    for (int mt = 0; mt < 2; mt++)
#pragma unroll
      for (int r = 0; r < 4; r++) {
        int rl = mt * 16 + quad * 4 + r;
        X2s[rl * 264 + n] = (bf16_t)((hreg[mt][nt][r] - rsum[mt][r]) * rsq[mt][r] * sv + bv);
      }
  }
  __syncthreads();

  // ---------------- Phase A: h1 = relu(x2m @ W1 + b1) -> H1s ----------------
#pragma unroll
  for (int s = 0; s < 2; s++) {
    const bf16_t* Wsrc = W1T + (size_t)s * 256 * 256;
    f32x4 acc_a[4][2] = {};
    stage256(Wsrc, Wbuf[0], tid, 256, 0);
#pragma unroll
    for (int t = 0; t < 4; t++) {
      int buf = t & 1;
      if (t + 1 < 4) stage256(Wsrc, Wbuf[buf ^ 1], tid, 256, (t + 1) * 64);
      __syncthreads();
#pragma unroll
      for (int ks = 0; ks < 2; ks++) {
        bf16x8 af[4];
#pragma unroll
        for (int mt = 0; mt < 4; mt++) {
          int row = w * 64 + mt * 16 + n16;
          int cd = (ks * 4 + quad) ^ (row & 7);
          af[mt] = *(const bf16x8*)(Wbuf[buf] + row * 64 + cd * 8);
        }
        bf16x8 xf[2];
#pragma unroll
        for (int nt = 0; nt < 2; nt++)
          xf[nt] = *(const bf16x8*)(X2s + (nt * 16 + n16) * 264 + t * 64 + ks * 32 + quad * 8);
#pragma unroll
        for (int mt = 0; mt < 4; mt++)
#pragma unroll
          for (int nt = 0; nt < 2; nt++)
            acc_a[mt][nt] = __builtin_amdgcn_mfma_f32_16x16x32_bf16(
                af[mt], xf[nt], acc_a[mt][nt], 0, 0, 0);
      }
      __syncthreads();
    }
#pragma unroll
    for (int mt = 0; mt < 4; mt++) {
      int hid0 = s * 256 + w * 64 + mt * 16 + quad * 4;
      float b1v0 = b1[hid0], b1v1 = b1[hid0 + 1], b1v2 = b1[hid0 + 2], b1v3 = b1[hid0 + 3];
      int c = hid0 >> 3;
      int off4 = (quad & 1) * 4;
#pragma unroll
      for (int nt = 0; nt < 2; nt++) {
        int tok = nt * 16 + n16;
        bf16x4 o = {(bf16_t)fmaxf(acc_a[mt][nt][0] + b1v0, 0.0f),
                    (bf16_t)fmaxf(acc_a[mt][nt][1] + b1v1, 0.0f),
                    (bf16_t)fmaxf(acc_a[mt][nt][2] + b1v2, 0.0f),
                    (bf16_t)fmaxf(acc_a[mt][nt][3] + b1v3, 0.0f)};
        int cs = c ^ (n16 & 7);
        *(bf16x4*)(H1s + tok * 512 + cs * 8 + off4) = o;
      }
    }
  }
  __syncthreads();

  // ---------------- Phase B: h' = h + h1 @ W2 + b2 (+LN_next) ----------------
  f32x4 acc[2][4] = {};
  stage256(W2T, Wbuf[0], tid, 512, 0);
#pragma unroll
  for (int s = 0; s < 8; s++) {
    int buf = s & 1;
    if (s + 1 < 8) stage256(W2T, Wbuf[buf ^ 1], tid, 512, (s + 1) * 64);
    __syncthreads();
#pragma unroll
    for (int ks = 0; ks < 2; ks++) {
      bf16x8 af2[2];
#pragma unroll
      for (int mt = 0; mt < 2; mt++) {
        int tok = mt * 16 + n16;
        int g = (s * 8 + ks * 4 + quad) ^ (n16 & 7);
        af2[mt] = *(const bf16x8*)(H1s + tok * 512 + g * 8);
      }
      bf16x8 bf2[4];
#pragma unroll
      for (int nt = 0; nt < 4; nt++) {
        int rowb = w * 64 + nt * 16 + n16;
        int cd = (ks * 4 + quad) ^ (rowb & 7);
        bf2[nt] = *(const bf16x8*)(Wbuf[buf] + rowb * 64 + cd * 8);
      }
#pragma unroll
      for (int mt = 0; mt < 2; mt++)
#pragma unroll
        for (int nt = 0; nt < 4; nt++)
          acc[mt][nt] = __builtin_amdgcn_mfma_f32_16x16x32_bf16(
              af2[mt], bf2[nt], acc[mt][nt], 0, 0, 0);
    }
    __syncthreads();
  }

#pragma unroll
  for (int mt = 0; mt < 2; mt++)
#pragma unroll
    for (int r = 0; r < 4; r++) { rsum[mt][r] = 0.f; rsq[mt][r] = 0.f; }
#pragma unroll
  for (int nt = 0; nt < 4; nt++) {
    int n = w * 64 + nt * 16 + n16;
    float bv = b2[n];
#pragma unroll
    for (int mt = 0; mt < 2; mt++)
#pragma unroll
      for (int r = 0; r < 4; r++) {
        int m = m0 + mt * 16 + quad * 4 + r;
        float hv = hreg[mt][nt][r] + acc[mt][nt][r] + bv;
        outf[(size_t)m * DIM + n] = hv;
        acc[mt][nt][r] = hv;
        rsum[mt][r] += hv;
        rsq[mt][r] += hv * hv;
      }
  }

  if (LNOUT) {
#pragma unroll
    for (int mt = 0; mt < 2; mt++)
#pragma unroll
      for (int r = 0; r < 4; r++) {
        float s_ = rsum[mt][r], q_ = rsq[mt][r];
#pragma unroll
        for (int off = 1; off < 16; off <<= 1) {
          s_ += __shfl_xor(s_, off);
          q_ += __shfl_xor(q_, off);
        }
        rsum[mt][r] = s_;
        rsq[mt][r] = q_;
      }
    if (n16 == 0) {
#pragma unroll
      for (int mt = 0; mt < 2; mt++)
#pragma unroll
        for (int r = 0; r < 4; r++)
          stats[w][mt * 16 + quad * 4 + r] = make_float2(rsum[mt][r], rsq[mt][r]);
    }
    __syncthreads();
#pragma unroll
    for (int mt = 0; mt < 2; mt++)
#pragma unroll
      for (int r = 0; r < 4; r++) {
        int lr = mt * 16 + quad * 4 + r;
        float2 t0 = stats[0][lr], t1 = stats[1][lr], t2 = stats[2][lr], t3 = stats[3][lr];
        float tot = t0.x + t1.x + t2.x + t3.x;
        float totq = t0.y + t1.y + t2.y + t3.y;
        float mean = tot * (1.0f / 256.0f);
        float var = totq * (1.0f / 256.0f) - mean * mean;
        rsum[mt][r] = mean;
        rsq[mt][r] = rsqrtf(var + 1e-5f);
      }
#pragma unroll
    for (int nt = 0; nt < 4; nt++) {
      int n = w * 64 + nt * 16 + n16;
      float sv = ls1n[n], bv = lb1n[n];
#pragma unroll
      for (int mt = 0; mt < 2; mt++)
#pragma unroll
        for (int r = 0; r < 4; r++) {
          int m = m0 + mt * 16 + quad * 4 + r;
          float x2v = (acc[mt][nt][r] - rsum[mt][r]) * rsq[mt][r] * sv + bv;
          outb[(size_t)m * DIM + n] = (bf16_t)x2v;
        }
    }
  }
}

// ---------------------------------------------------------------------------
// Flash attention v8 (best: 51.2 us): 32 q/wave, S^T trick, ones-MFMA row
// sums, software-pipelined P (double-buffered LDS), register K/V prefetch.
// grid (32 bh, 32 qblk), 128 threads.
// ---------------------------------------------------------------------------
__global__ __launch_bounds__(128) void flash8_kernel(
    const bf16_t* __restrict__ Q, const bf16_t* __restrict__ K,
    const bf16_t* __restrict__ VT, bf16_t* __restrict__ OB) {
  __shared__ __align__(16) bf16_t Plds[2][2][32][72];
  int bh = blockIdx.x;
  int q0 = blockIdx.y * 64;
  int w = threadIdx.x >> 6;
  int lane = threadIdx.x & 63;
  int n16 = lane & 15;
  int quad = lane >> 4;

  const bf16_t* Qb = Q + (size_t)bh * SEQ * DK;
  const bf16_t* Kb = K + (size_t)bh * SEQ * DK;
  const bf16_t* Vb = VT + (size_t)bh * DK * SEQ;
  int qr0 = q0 + w * 32;

  bf16x8 qfrag[2];
#pragma unroll
  for (int qg = 0; qg < 2; qg++)
    qfrag[qg] = *(const bf16x8*)(Qb + (size_t)(qr0 + qg * 16 + n16) * DK + quad * 8);

  bf16_t one = (bf16_t)1.0f;
  bf16x8 ones = {one, one, one, one, one, one, one, one};

  f32x4 oacc[2][2] = {};
  f32x4 lacc[2] = {};

  {
    bf16x8 kf0[4];
#pragma unroll
    for (int t = 0; t < 4; t++)
      kf0[t] = *(const bf16x8*)(Kb + (size_t)(t * 16 + n16) * DK + quad * 8);
#pragma unroll
    for (int qg = 0; qg < 2; qg++)
#pragma unroll
      for (int t = 0; t < 4; t++) {
        f32x4 sc = __builtin_amdgcn_mfma_f32_16x16x32_bf16(
            kf0[t], qfrag[qg], (f32x4){0.f, 0.f, 0.f, 0.f}, 0, 0, 0);
        bf16x4 pf;
#pragma unroll
        for (int r = 0; r < 4; r++) pf[r] = (bf16_t)FAST_EXP2(sc[r]);
        *(bf16x4*)&Plds[0][w][qg * 16 + n16][t * 16 + quad * 4] = pf;
      }
  }
  bf16x8 kfS[4], vfP[2][2];
#pragma unroll
  for (int t = 0; t < 4; t++)
    kfS[t] = *(const bf16x8*)(Kb + (size_t)(64 + t * 16 + n16) * DK + quad * 8);
#pragma unroll
  for (int c = 0; c < 2; c++) {
    vfP[c][0] = *(const bf16x8*)(Vb + (size_t)n16 * SEQ + c * 32 + quad * 8);
    vfP[c][1] = *(const bf16x8*)(Vb + (size_t)(16 + n16) * SEQ + c * 32 + quad * 8);
  }

#pragma unroll 2
  for (int i = 0; i < 32; i++) {
    int buf = i & 1;
    bf16x8 pf8[2][2];
#pragma unroll
    for (int qg = 0; qg < 2; qg++)
#pragma unroll
      for (int c = 0; c < 2; c++)
        pf8[qg][c] = *(const bf16x8*)&Plds[buf][w][qg * 16 + n16][c * 32 + quad * 8];
    bf16x8 kfN[4], vfN[2][2];
    if (i + 2 < 32) {
      int kb = (i + 2) * 64;
#pragma unroll
      for (int t = 0; t < 4; t++)
        kfN[t] = *(const bf16x8*)(Kb + (size_t)(kb + t * 16 + n16) * DK + quad * 8);
    }
    if (i + 1 < 32) {
      int kb = (i + 1) * 64;
#pragma unroll
      for (int c = 0; c < 2; c++) {
        vfN[c][0] = *(const bf16x8*)(Vb + (size_t)n16 * SEQ + kb + c * 32 + quad * 8);
        vfN[c][1] = *(const bf16x8*)(Vb + (size_t)(16 + n16) * SEQ + kb + c * 32 + quad * 8);
      }
    }
    if (i + 1 < 32) {
#pragma unroll
      for (int qg = 0; qg < 2; qg++)
#pragma unroll
        for (int t = 0; t < 4; t++) {
          f32x4 sc = __builtin_amdgcn_mfma_f32_16x16x32_bf16(
              kfS[t], qfrag[qg], (f32x4){0.f, 0.f, 0.f, 0.f}, 0, 0, 0);
          bf16x4 pf;
#pragma unroll
          for (int r = 0; r < 4; r++) pf[r] = (bf16_t)FAST_EXP2(sc[r]);
          *(bf16x4*)&Plds[buf ^ 1][w][qg * 16 + n16][t * 16 + quad * 4] = pf;
        }
    }
#pragma unroll
    for (int qg = 0; qg < 2; qg++)
#pragma unroll
      for (int c = 0; c < 2; c++) {
        lacc[qg] = __builtin_amdgcn_mfma_f32_16x16x32_bf16(pf8[qg][c], ones, lacc[qg], 0, 0, 0);
        oacc[qg][0] = __builtin_amdgcn_mfma_f32_16x16x32_bf16(pf8[qg][c], vfP[c][0], oacc[qg][0], 0, 0, 0);
        oacc[qg][1] = __builtin_amdgcn_mfma_f32_16x16x32_bf16(pf8[qg][c], vfP[c][1], oacc[qg][1], 0, 0, 0);
      }
    if (i + 2 < 32) {
#pragma unroll
      for (int t = 0; t < 4; t++) kfS[t] = kfN[t];
    }
    if (i + 1 < 32) {
#pragma unroll
      for (int c = 0; c < 2; c++) {
        vfP[c][0] = vfN[c][0];
        vfP[c][1] = vfN[c][1];
      }
    }
  }

  int bb = bh >> 3, hh = bh & 7;
#pragma unroll
  for (int qg = 0; qg < 2; qg++)
#pragma unroll
    for (int r = 0; r < 4; r++) {
      float linv = 1.0f / lacc[qg][r];
      int row = qr0 + qg * 16 + quad * 4 + r;
      bf16_t* op = OB + ((size_t)(bb * SEQ + row)) * DIM + hh * DK;
      op[n16] = (bf16_t)(oacc[qg][0][r] * linv);
      op[16 + n16] = (bf16_t)(oacc[qg][1][r] * linv);
    }
}

// ---------------------------------------------------------------------------
extern "C" void kernel_launch(void* const* d_in, const int* in_sizes, int n_in,
                              void* d_out, int out_size, void* d_ws, size_t ws_size,
                              hipStream_t stream) {
  const float* x     = (const float*)d_in[0];
  const float* ln0_s = (const float*)d_in[1];
  const float* ln0_b = (const float*)d_in[2];
  const float* ln1_s = (const float*)d_in[3];
  const float* ln1_b = (const float*)d_in[4];
  const float* ln2_s = (const float*)d_in[5];
  const float* ln2_b = (const float*)d_in[6];
  const float* wq = (const float*)d_in[7];
  const float* bq = (const float*)d_in[8];
  const float* wk = (const float*)d_in[9];
  const float* bk = (const float*)d_in[10];
  const float* wv = (const float*)d_in[11];
  const float* bv = (const float*)d_in[12];
  const float* wo = (const float*)d_in[13];
  const float* bo = (const float*)d_in[14];
  const float* w1 = (const float*)d_in[15];
  const float* b1 = (const float*)d_in[16];
  const float* w2 = (const float*)d_in[17];
  const float* b2 = (const float*)d_in[18];

  float* out = (float*)d_out;  // h (fp32 residual stream) lives here
  const size_t ACT = (size_t)8192 * DIM;  // 2,097,152

  bf16_t* wsb = (bf16_t*)d_ws;
  bf16_t* x2b = wsb;                 // ACT
  bf16_t* obf = x2b + ACT;           // ACT
  bf16_t* qbf = obf + ACT;           // ACT
  bf16_t* kbf = qbf + ACT;           // ACT
  bf16_t* vbf = kbf + ACT;           // ACT (transposed [B,H,DK,S])
  bf16_t* WqT = vbf + ACT;           // 4 x 65536
  bf16_t* WkT = WqT + 4 * 65536;
  bf16_t* WvT = WkT + 4 * 65536;
  bf16_t* WoT = WvT + 4 * 65536;
  bf16_t* W1T = WoT + 4 * 65536;     // 4 x 131072
  bf16_t* W2T = W1T + 4 * 131072;    // 4 x 131072

  dim3 blk(256);
  dim3 blkF(128);
  dim3 gLN(2048);
  dim3 gRow(256);
  dim3 gQKV(6, 64);
  dim3 gAtt(32, 32);

  wtrans_all_kernel<<<dim3(512), blk, 0, stream>>>(wq, wk, wv, wo, w1, w2,
                                                   WqT, WkT, WvT, WoT, W1T, W2T);

  // h = LN(x, ln0); x2 = LN(h, ln1[0])
  ln_double_kernel<<<gLN, blk, 0, stream>>>(x, ln0_s, ln0_b, ln1_s, ln1_b, out, x2b);

  for (int l = 0; l < 4; l++) {
    bf16_t* WqTl = WqT + (size_t)l * 65536;
    bf16_t* WkTl = WkT + (size_t)l * 65536;
    bf16_t* WvTl = WvT + (size_t)l * 65536;
    bf16_t* WoTl = WoT + (size_t)l * 65536;
    bf16_t* W1Tl = W1T + (size_t)l * 131072;
    bf16_t* W2Tl = W2T + (size_t)l * 131072;

    // fused q,k,v projections
    qkv9_kernel<<<gQKV, blk, 0, stream>>>(x2b, WqTl, WkTl, WvTl,
                                          bq + l * DIM, bk + l * DIM, bv + l * DIM,
                                          qbf, kbf, vbf);
    // attention
    flash8_kernel<<<gAtt, blkF, 0, stream>>>(qbf, kbf, vbf, obf);
    // fused tail: Wo-proj + resid + LN2 + FFN + resid + LN1_next
    if (l < 3) {
      tail_kernel<1><<<gRow, blk, 0, stream>>>(
          obf, WoTl, bo + l * DIM, W1Tl, W2Tl, b1 + l * FF, b2 + l * DIM,
          ln2_s + l * DIM, ln2_b + l * DIM, out,
          ln1_s + (l + 1) * DIM, ln1_b + (l + 1) * DIM, x2b);
    } else {
      tail_kernel<0><<<gRow, blk, 0, stream>>>(
          obf, WoTl, bo + l * DIM, W1Tl, W2Tl, b1 + l * FF, b2 + l * DIM,
          ln2_s + l * DIM, ln2_b + l * DIM, out,
          nullptr, nullptr, nullptr);
    }
  }
}